// Round 14
// baseline (877.819 us; speedup 1.0000x reference)
//
#include <hip/hip_runtime.h>

// LSTMPredictor: B=1024, T=512, IN=19, H=128, OUT=7 (fp32 in/out)
// L1: R11-proven kernel verbatim (~250 us).
// L2: producer/consumer (R13-proven: 60 VGPR + 64 AGPR, 16 waves/CU, glds h1
//     ring w/ counted vmcnt) + R14 LDS-pipe cuts:
//  (1) pre-swizzled glds SOURCE (m173): lane l loads global chunk
//      (l&48)|((l&15)^((l>>3)&6)) so LDS holds row r chunk c at r*16+(c^2r);
//      producer frag reads use matching offsets -> 4-way bank conflict -> 2-way.
//  (2) ring recompacted: [slot][col][16 fp16 + 4 pad] (40B stride = perfect
//      16-bank permutation): producer 2 ds_write_b128, consumer 2 ds_read_b128
//      (was 4+4 wider ops); cvts moved to underutilized VALU.
// D-layout row-dup invariant (R3): A-frag rows dup mod 4 -> acc_g[r] at every
// lane holds D_g[r][col]; lane (lg,lc) selects its own reg lg (sel4).

typedef _Float16 half8 __attribute__((ext_vector_type(8)));
typedef float f32x4 __attribute__((ext_vector_type(4)));

#define MFMA16(a, b, c) __builtin_amdgcn_mfma_f32_16x16x32_f16((a), (b), (c), 0, 0, 0)
#define BARRIER() asm volatile("s_waitcnt lgkmcnt(0)\ns_barrier" ::: "memory")
#define D_AHEAD 4
#define NSLOT 5

__device__ __forceinline__ void pin(half8& v) { asm volatile("" : "+v"(v)); }

__device__ __forceinline__ void glds16(const _Float16* g, _Float16* l) {
  __builtin_amdgcn_global_load_lds(
      (const __attribute__((address_space(1))) void*)g,
      (__attribute__((address_space(3))) void*)l, 16, 0, 0);
}

__device__ __forceinline__ float sigf(float x) {
  return __builtin_amdgcn_rcpf(1.f + __expf(-x));   // NaN-free at +/-inf
}
__device__ __forceinline__ float tanhf_(float x) {
  return 1.f - 2.f * __builtin_amdgcn_rcpf(1.f + __expf(2.f * x));  // NaN-free
}
// acc_g[r] == D_g[r][lc] at every lane (duplication invariant) -> pick reg lg.
__device__ __forceinline__ float sel4(const f32x4 a, const int lg) {
  const float v01 = (lg & 1) ? a[1] : a[0];
  const float v23 = (lg & 1) ? a[3] : a[2];
  return (lg & 2) ? v23 : v01;
}

// ---------------- Layer 1 (R3/R11-proven, verbatim) ----------------
__global__ __launch_bounds__(512) void lstm_layer1_kernel(
    const float* __restrict__ x,        // [1024,512,19]
    const float* __restrict__ Wih,      // [512,19]
    const float* __restrict__ Whh,      // [512,128]
    const float* __restrict__ bih, const float* __restrict__ bhh,
    _Float16* __restrict__ h1g)         // [512][1024][128] fp16 (T-major)
{
  __shared__ _Float16 xls[512][12][8];  // 98,304 B
  __shared__ _Float16 hbuf[2][64][8];   // 2 KiB
  const int tid = threadIdx.x, bid = blockIdx.x;
  const int wv = tid >> 6, lane = tid & 63;
  const int lg = lane >> 4, lc = lane & 15;
  const int col = wv * 16 + lc;
  const int off0 = lg * 32 + (lc & 3) * 8;
  const int woff = ((wv * 2 + (lc >> 3)) * 4 + lg) * 8 + (lc & 7);

  half8 wih_f[4], whh_f[4][4];
  float bias[4];
#pragma unroll
  for (int g = 0; g < 4; ++g) {
    const int n = g * 128 + col;
    bias[g] = bih[n] + bhh[n];
    half8 f;
#pragma unroll
    for (int j = 0; j < 8; ++j) {
      const int k = lg * 8 + j;
      f[j] = (_Float16)((k < 19) ? Wih[n * 19 + k] : 0.f);
    }
    wih_f[g] = f;
#pragma unroll
    for (int kk = 0; kk < 4; ++kk) {
      const float* p = Whh + n * 128 + kk * 32 + lg * 8;
      half8 f2;
#pragma unroll
      for (int j = 0; j < 8; ++j) f2[j] = (_Float16)p[j];
      whh_f[g][kk] = f2;
    }
  }

  for (int i2 = tid; i2 < 512 * 96; i2 += 512) {
    const int t = i2 / 96, r = i2 - t * 96;
    const int cc = r >> 5, rr = (r >> 3) & 3, j = r & 7;
    const int k = cc * 8 + j;
    float v = 0.f;
    if (k < 19) v = x[((size_t)(bid * 4 + rr) * 512 + t) * 19 + k];
    xls[t][cc * 4 + rr][j] = (_Float16)v;
  }
  for (int i = tid; i < 1024; i += 512) ((_Float16*)hbuf)[i] = (_Float16)0.f;
  __syncthreads();

  float c = 0.f;
  _Float16* h1p = h1g + (size_t)(bid * 4 + lg) * 128 + col;
  const _Float16* xb = &xls[0][0][0] + off0;
  _Float16* hb0p = &hbuf[0][0][0];
  const f32x4 fz = {0.f, 0.f, 0.f, 0.f};
  const bool xv = (lg < 3);

#define L1_STEP(T, RD, WR)                                                    \
  {                                                                           \
    const _Float16* rd = (RD) + off0;                                         \
    const half8 hb0 = *(const half8*)(rd);                                    \
    const half8 hb1 = *(const half8*)(rd + 128);                              \
    const half8 hb2 = *(const half8*)(rd + 256);                              \
    const half8 hb3 = *(const half8*)(rd + 384);                              \
    half8 ax = {};                                                            \
    if (xv) ax = *(const half8*)(xb + (T) * 96);                              \
    f32x4 a0 = MFMA16(ax, wih_f[0], fz);                                      \
    f32x4 a1 = MFMA16(ax, wih_f[1], fz);                                      \
    f32x4 a2 = MFMA16(ax, wih_f[2], fz);                                      \
    f32x4 a3 = MFMA16(ax, wih_f[3], fz);                                      \
    a0 = MFMA16(hb0, whh_f[0][0], a0); a1 = MFMA16(hb0, whh_f[1][0], a1);     \
    a2 = MFMA16(hb0, whh_f[2][0], a2); a3 = MFMA16(hb0, whh_f[3][0], a3);     \
    a0 = MFMA16(hb1, whh_f[0][1], a0); a1 = MFMA16(hb1, whh_f[1][1], a1);     \
    a2 = MFMA16(hb1, whh_f[2][1], a2); a3 = MFMA16(hb1, whh_f[3][1], a3);     \
    a0 = MFMA16(hb2, whh_f[0][2], a0); a1 = MFMA16(hb2, whh_f[1][2], a1);     \
    a2 = MFMA16(hb2, whh_f[2][2], a2); a3 = MFMA16(hb2, whh_f[3][2], a3);     \
    a0 = MFMA16(hb3, whh_f[0][3], a0); a1 = MFMA16(hb3, whh_f[1][3], a1);     \
    a2 = MFMA16(hb3, whh_f[2][3], a2); a3 = MFMA16(hb3, whh_f[3][3], a3);     \
    const float gi = sel4(a0, lg) + bias[0];                                  \
    const float gf = sel4(a1, lg) + bias[1];                                  \
    const float gg = sel4(a2, lg) + bias[2];                                  \
    const float go = sel4(a3, lg) + bias[3];                                  \
    const float I = sigf(gi), F = sigf(gf), G = tanhf_(gg), O = sigf(go);     \
    c = F * c + I * G;                                                        \
    const float h = O * tanhf_(c);                                            \
    const _Float16 h16 = (_Float16)h;                                         \
    (WR)[woff] = h16;                                                         \
    h1p[(size_t)(T) * 131072] = h16;                                          \
    BARRIER();                                                                \
  }

#pragma unroll 1
  for (int t = 0; t < 512; t += 2) {
    L1_STEP(t, hb0p + 512, hb0p);
    L1_STEP(t + 1, hb0p, hb0p + 512);
  }
#undef L1_STEP
}

// ------- Layer 2 + Linear: producer/consumer + swizzled glds h1 ring -------
__global__ __launch_bounds__(1024) void lstm_layer2_pc(
    const _Float16* __restrict__ h1g,   // [512][1024][128]
    const float* __restrict__ Wih,      // [512,128]
    const float* __restrict__ Whh,      // [512,128]
    const float* __restrict__ bih, const float* __restrict__ bhh,
    const float* __restrict__ Wlin,     // [7,128]
    const float* __restrict__ blin,     // [7]
    float* __restrict__ out)            // [1024, 3584]
{
  __shared__ _Float16 ring2[NSLOT][128 * 20];  // 25.6 KB: [slot][col][16 a-vals + 4 pad]
  __shared__ _Float16 h1s[4][512];             // 4 KiB: h1 glds ring (chunk-swizzled)
  __shared__ _Float16 h2b[2][512];             // 2 KiB
  __shared__ _Float16 wlls[16][136];           // Wlin staged
  const int tid = threadIdx.x, bid = blockIdx.x;
  const int wv = tid >> 6, lane = tid & 63;
  const int lg = lane >> 4, lc = lane & 15;
  const bool isCons = (wv < 8);
  const int cw = isCons ? wv : (wv - 8);
  const int col = cw * 16 + lc;
  const int off0 = lg * 32 + (lc & 3) * 8;
  const int woff = ((col >> 3) * 4 + lg) * 8 + (col & 7);

  for (int i = tid; i < 16 * 128; i += 1024)
    wlls[i >> 7][i & 127] = (_Float16)((i < 7 * 128) ? Wlin[i] : 0.f);
  for (int i = tid; i < 1024; i += 1024) ((_Float16*)h2b)[i] = (_Float16)0.f;

  // Pre-swizzled glds source: lane l loads global chunk (row*16 + (c ^ 2*row))
  // so LDS chunk l = row*16+c' holds row r chunk c with c' = c ^ 2r.
  const int gchunk = (lane & 48) | ((lane & 15) ^ ((lane >> 3) & 6));
  const _Float16* h1base = h1g + (size_t)bid * 512 + gchunk * 8;
  if (wv == 8) {
    glds16(h1base, &h1s[0][0]);
    glds16(h1base + 131072, &h1s[1][0]);
    glds16(h1base + 262144, &h1s[2][0]);
    asm volatile("s_waitcnt vmcnt(2)" ::: "memory");   // slot 0 complete
  }

  if (isCons) {
    // ---------------- Consumer: recurrence (wh2 only) ----------------
    half8 wh_f[4][4];
#pragma unroll
    for (int g = 0; g < 4; ++g) {
      const int n = g * 128 + col;
#pragma unroll
      for (int kk = 0; kk < 4; ++kk) {
        const float* p = Whh + n * 128 + kk * 32 + lg * 8;
        half8 f;
#pragma unroll
        for (int j = 0; j < 8; ++j) f[j] = (_Float16)p[j];
        wh_f[g][kk] = f;
      }
      pin(wh_f[g][0]); pin(wh_f[g][1]); pin(wh_f[g][2]); pin(wh_f[g][3]);
    }
    const bool yv = (lc < 7);
    const float ybias = yv ? blin[lc] : 0.f;
    __syncthreads();

    float c = 0.f;
    int slotR = 0;
#pragma unroll 1
    for (int it = 0; it < 512 + D_AHEAD; ++it) {
      if (it >= D_AHEAD) {
        const int t = it - D_AHEAD;
        const int pb = t & 1;
        const _Float16* rd = &h2b[pb ^ 1][0] + off0;
        const half8 q0 = *(const half8*)(rd);
        const half8 q1 = *(const half8*)(rd + 128);
        const half8 q2 = *(const half8*)(rd + 256);
        const half8 q3 = *(const half8*)(rd + 384);
        const _Float16* rp = &ring2[slotR][0] + col * 20;
        const half8 rlo = *(const half8*)(rp);
        const half8 rhi = *(const half8*)(rp + 8);
        f32x4 a0 = {(float)rlo[0], (float)rlo[1], (float)rlo[2], (float)rlo[3]};
        f32x4 a1 = {(float)rlo[4], (float)rlo[5], (float)rlo[6], (float)rlo[7]};
        f32x4 a2 = {(float)rhi[0], (float)rhi[1], (float)rhi[2], (float)rhi[3]};
        f32x4 a3 = {(float)rhi[4], (float)rhi[5], (float)rhi[6], (float)rhi[7]};
        __builtin_amdgcn_s_setprio(1);
        a0 = MFMA16(q0, wh_f[0][0], a0); a1 = MFMA16(q0, wh_f[1][0], a1);
        a2 = MFMA16(q0, wh_f[2][0], a2); a3 = MFMA16(q0, wh_f[3][0], a3);
        a0 = MFMA16(q1, wh_f[0][1], a0); a1 = MFMA16(q1, wh_f[1][1], a1);
        a2 = MFMA16(q1, wh_f[2][1], a2); a3 = MFMA16(q1, wh_f[3][1], a3);
        a0 = MFMA16(q2, wh_f[0][2], a0); a1 = MFMA16(q2, wh_f[1][2], a1);
        a2 = MFMA16(q2, wh_f[2][2], a2); a3 = MFMA16(q2, wh_f[3][2], a3);
        a0 = MFMA16(q3, wh_f[0][3], a0); a1 = MFMA16(q3, wh_f[1][3], a1);
        a2 = MFMA16(q3, wh_f[2][3], a2); a3 = MFMA16(q3, wh_f[3][3], a3);
        __builtin_amdgcn_s_setprio(0);
        // y(t-1) from q = h2(t-1); wave 0 only
        if (wv == 0 && t > 0) {
          const _Float16* wlp = &wlls[lc][0] + lg * 8;
          f32x4 ya = {ybias, ybias, ybias, ybias};
          {
            const half8 w0 = *(const half8*)(wlp);
            const half8 w1 = *(const half8*)(wlp + 32);
            ya = MFMA16(q0, w0, ya);
            ya = MFMA16(q1, w1, ya);
          }
          {
            const half8 w2 = *(const half8*)(wlp + 64);
            const half8 w3 = *(const half8*)(wlp + 96);
            ya = MFMA16(q2, w2, ya);
            ya = MFMA16(q3, w3, ya);
          }
          if (lg == 0 && yv) {
#pragma unroll
            for (int j = 0; j < 4; ++j)
              out[(size_t)(bid * 4 + j) * 3584 + (size_t)(t - 1) * 7 + lc] = ya[j];
          }
        }
        const float gi = sel4(a0, lg), gf = sel4(a1, lg);
        const float gg = sel4(a2, lg), go = sel4(a3, lg);
        const float I = sigf(gi), F = sigf(gf), G = tanhf_(gg), O = sigf(go);
        c = F * c + I * G;
        h2b[pb][woff] = (_Float16)(O * tanhf_(c));
        if (++slotR == NSLOT) slotR = 0;
      }
      BARRIER();
    }
    // final y(511): h2(511) in h2b[1]
    if (wv == 0) {
      const _Float16* rd = &h2b[1][0] + off0;
      const half8 q0 = *(const half8*)(rd);
      const half8 q1 = *(const half8*)(rd + 128);
      const half8 q2 = *(const half8*)(rd + 256);
      const half8 q3 = *(const half8*)(rd + 384);
      const _Float16* wlp = &wlls[lc][0] + lg * 8;
      const half8 w0 = *(const half8*)(wlp);
      const half8 w1 = *(const half8*)(wlp + 32);
      const half8 w2 = *(const half8*)(wlp + 64);
      const half8 w3 = *(const half8*)(wlp + 96);
      f32x4 ya = {ybias, ybias, ybias, ybias};
      ya = MFMA16(q0, w0, ya);
      ya = MFMA16(q1, w1, ya);
      ya = MFMA16(q2, w2, ya);
      ya = MFMA16(q3, w3, ya);
      if (lg == 0 && yv) {
#pragma unroll
        for (int j = 0; j < 4; ++j)
          out[(size_t)(bid * 4 + j) * 3584 + (size_t)511 * 7 + lc] = ya[j];
      }
    }
  } else {
    // ---------- Producer: a(t) = bias2 + wi2*h1(t), D ahead, swizzled h1s ----------
    half8 wi_f[4][4];
    float bias_s[4];
#pragma unroll
    for (int g = 0; g < 4; ++g) {
      const int n = g * 128 + col;
      bias_s[g] = bih[n] + bhh[n];
#pragma unroll
      for (int kk = 0; kk < 4; ++kk) {
        const float* p = Wih + n * 128 + kk * 32 + lg * 8;
        half8 f;
#pragma unroll
        for (int j = 0; j < 8; ++j) f[j] = (_Float16)p[j];
        wi_f[g][kk] = f;
      }
      pin(wi_f[g][0]); pin(wi_f[g][1]); pin(wi_f[g][2]); pin(wi_f[g][3]);
    }
    const f32x4 bV0 = {bias_s[0], bias_s[0], bias_s[0], bias_s[0]};
    const f32x4 bV1 = {bias_s[1], bias_s[1], bias_s[1], bias_s[1]};
    const f32x4 bV2 = {bias_s[2], bias_s[2], bias_s[2], bias_s[2]};
    const f32x4 bV3 = {bias_s[3], bias_s[3], bias_s[3], bias_s[3]};
    // swizzled h1s read offsets (halfs): chunk = row*16 + ((kk*4+lg) ^ 2*row)
    const int hrow = lc & 3;
    int hofs[4];
#pragma unroll
    for (int kk = 0; kk < 4; ++kk)
      hofs[kk] = hrow * 128 + (((kk * 4 + lg) ^ (hrow << 1)) << 3);
    __syncthreads();

    const bool wr = (lg == 0);
    int slotW = 0;
#pragma unroll 1
    for (int it = 0; it < 512 + D_AHEAD; ++it) {
      if (it < 512) {
        // issue h1(it+3) into LDS ring, 3 barrier-intervals ahead
        if (wv == 8 && it + 3 < 512)
          glds16(h1base + (size_t)(it + 3) * 131072, &h1s[(it + 3) & 3][0]);
        const _Float16* hp = &h1s[it & 3][0];
        const half8 p0 = *(const half8*)(hp + hofs[0]);
        const half8 p1 = *(const half8*)(hp + hofs[1]);
        const half8 p2 = *(const half8*)(hp + hofs[2]);
        const half8 p3 = *(const half8*)(hp + hofs[3]);
        f32x4 a0 = MFMA16(p0, wi_f[0][0], bV0);
        f32x4 a1 = MFMA16(p0, wi_f[1][0], bV1);
        f32x4 a2 = MFMA16(p0, wi_f[2][0], bV2);
        f32x4 a3 = MFMA16(p0, wi_f[3][0], bV3);
        a0 = MFMA16(p1, wi_f[0][1], a0); a1 = MFMA16(p1, wi_f[1][1], a1);
        a2 = MFMA16(p1, wi_f[2][1], a2); a3 = MFMA16(p1, wi_f[3][1], a3);
        a0 = MFMA16(p2, wi_f[0][2], a0); a1 = MFMA16(p2, wi_f[1][2], a1);
        a2 = MFMA16(p2, wi_f[2][2], a2); a3 = MFMA16(p2, wi_f[3][2], a3);
        a0 = MFMA16(p3, wi_f[0][3], a0); a1 = MFMA16(p3, wi_f[1][3], a1);
        a2 = MFMA16(p3, wi_f[2][3], a2); a3 = MFMA16(p3, wi_f[3][3], a3);
        if (wr) {
          _Float16* wp_ = &ring2[slotW][0] + col * 20;
          half8 lo, hi;
#pragma unroll
          for (int j = 0; j < 4; ++j) {
            lo[j] = (_Float16)a0[j];
            lo[j + 4] = (_Float16)a1[j];
            hi[j] = (_Float16)a2[j];
            hi[j + 4] = (_Float16)a3[j];
          }
          *(half8*)(wp_) = lo;
          *(half8*)(wp_ + 8) = hi;
        }
        // keep <=2 glds in flight; guarantees slot (it+1) complete
        if (wv == 8) asm volatile("s_waitcnt vmcnt(2)" ::: "memory");
        if (++slotW == NSLOT) slotW = 0;
      }
      BARRIER();
    }
  }
}

extern "C" void kernel_launch(void* const* d_in, const int* in_sizes, int n_in,
                              void* d_out, int out_size, void* d_ws, size_t ws_size,
                              hipStream_t stream) {
  (void)in_sizes; (void)n_in; (void)out_size; (void)ws_size;
  const float* x     = (const float*)d_in[0];
  const float* W_ih1 = (const float*)d_in[1];
  const float* W_hh1 = (const float*)d_in[2];
  const float* b_ih1 = (const float*)d_in[3];
  const float* b_hh1 = (const float*)d_in[4];
  const float* W_ih2 = (const float*)d_in[5];
  const float* W_hh2 = (const float*)d_in[6];
  const float* b_ih2 = (const float*)d_in[7];
  const float* b_hh2 = (const float*)d_in[8];
  const float* W_lin = (const float*)d_in[9];
  const float* b_lin = (const float*)d_in[10];
  float* out = (float*)d_out;
  _Float16* h1g = (_Float16*)d_ws;   // [512][1024][128] fp16 = 134,217,728 bytes

  lstm_layer1_kernel<<<256, 512, 0, stream>>>(x, W_ih1, W_hh1, b_ih1, b_hh1, h1g);
  lstm_layer2_pc<<<256, 1024, 0, stream>>>(h1g, W_ih2, W_hh2, b_ih2, b_hh2,
                                           W_lin, b_lin, out);
}

// Round 15
// 689.414 us; speedup vs baseline: 1.2733x; 1.2733x over previous
//
#include <hip/hip_runtime.h>

// LSTMPredictor: B=1024, T=512, IN=19, H=128, OUT=7 (fp32 in/out)
// L1: R11-proven kernel verbatim (~250 us).
// L2: producer/consumer (R13-proven core: glds h1 ring + counted vmcnt,
//     60 VGPR + 64 AGPR, 16 waves/CU) + R15 LDS-pipe cuts:
//  (1) R14-proven swizzled glds SOURCE for h1 (4-way -> 2-way conflicts).
//  (2) a-ring compacted to per-(col,row) gate quads, f32:
//      producer: sel4-transpose in regs (off-chain) -> ONE all-lane
//      ds_write_b128 of {i,f,g,o}(row=lg,col); consumer: ONE ds_read_b128,
//      added POST-chain (wh-chain runs from C=0). Ring DS ops 64->16/step;
//      zero cvts (the R14 regression is reverted).
// D-layout row-dup invariant (R3): A-frag rows dup mod 4 -> acc_g[r] at every
// lane holds D_g[r][col]; lane (lg,lc) selects its own reg lg (sel4).

typedef _Float16 half8 __attribute__((ext_vector_type(8)));
typedef float f32x4 __attribute__((ext_vector_type(4)));

#define MFMA16(a, b, c) __builtin_amdgcn_mfma_f32_16x16x32_f16((a), (b), (c), 0, 0, 0)
#define BARRIER() asm volatile("s_waitcnt lgkmcnt(0)\ns_barrier" ::: "memory")
#define D_AHEAD 4
#define NSLOT 5

__device__ __forceinline__ void pin(half8& v) { asm volatile("" : "+v"(v)); }

__device__ __forceinline__ void glds16(const _Float16* g, _Float16* l) {
  __builtin_amdgcn_global_load_lds(
      (const __attribute__((address_space(1))) void*)g,
      (__attribute__((address_space(3))) void*)l, 16, 0, 0);
}

__device__ __forceinline__ float sigf(float x) {
  return __builtin_amdgcn_rcpf(1.f + __expf(-x));   // NaN-free at +/-inf
}
__device__ __forceinline__ float tanhf_(float x) {
  return 1.f - 2.f * __builtin_amdgcn_rcpf(1.f + __expf(2.f * x));  // NaN-free
}
// acc_g[r] == D_g[r][lc] at every lane (duplication invariant) -> pick reg lg.
__device__ __forceinline__ float sel4(const f32x4 a, const int lg) {
  const float v01 = (lg & 1) ? a[1] : a[0];
  const float v23 = (lg & 1) ? a[3] : a[2];
  return (lg & 2) ? v23 : v01;
}

// ---------------- Layer 1 (R3/R11-proven, verbatim) ----------------
__global__ __launch_bounds__(512) void lstm_layer1_kernel(
    const float* __restrict__ x,        // [1024,512,19]
    const float* __restrict__ Wih,      // [512,19]
    const float* __restrict__ Whh,      // [512,128]
    const float* __restrict__ bih, const float* __restrict__ bhh,
    _Float16* __restrict__ h1g)         // [512][1024][128] fp16 (T-major)
{
  __shared__ _Float16 xls[512][12][8];  // 98,304 B
  __shared__ _Float16 hbuf[2][64][8];   // 2 KiB
  const int tid = threadIdx.x, bid = blockIdx.x;
  const int wv = tid >> 6, lane = tid & 63;
  const int lg = lane >> 4, lc = lane & 15;
  const int col = wv * 16 + lc;
  const int off0 = lg * 32 + (lc & 3) * 8;
  const int woff = ((wv * 2 + (lc >> 3)) * 4 + lg) * 8 + (lc & 7);

  half8 wih_f[4], whh_f[4][4];
  float bias[4];
#pragma unroll
  for (int g = 0; g < 4; ++g) {
    const int n = g * 128 + col;
    bias[g] = bih[n] + bhh[n];
    half8 f;
#pragma unroll
    for (int j = 0; j < 8; ++j) {
      const int k = lg * 8 + j;
      f[j] = (_Float16)((k < 19) ? Wih[n * 19 + k] : 0.f);
    }
    wih_f[g] = f;
#pragma unroll
    for (int kk = 0; kk < 4; ++kk) {
      const float* p = Whh + n * 128 + kk * 32 + lg * 8;
      half8 f2;
#pragma unroll
      for (int j = 0; j < 8; ++j) f2[j] = (_Float16)p[j];
      whh_f[g][kk] = f2;
    }
  }

  for (int i2 = tid; i2 < 512 * 96; i2 += 512) {
    const int t = i2 / 96, r = i2 - t * 96;
    const int cc = r >> 5, rr = (r >> 3) & 3, j = r & 7;
    const int k = cc * 8 + j;
    float v = 0.f;
    if (k < 19) v = x[((size_t)(bid * 4 + rr) * 512 + t) * 19 + k];
    xls[t][cc * 4 + rr][j] = (_Float16)v;
  }
  for (int i = tid; i < 1024; i += 512) ((_Float16*)hbuf)[i] = (_Float16)0.f;
  __syncthreads();

  float c = 0.f;
  _Float16* h1p = h1g + (size_t)(bid * 4 + lg) * 128 + col;
  const _Float16* xb = &xls[0][0][0] + off0;
  _Float16* hb0p = &hbuf[0][0][0];
  const f32x4 fz = {0.f, 0.f, 0.f, 0.f};
  const bool xv = (lg < 3);

#define L1_STEP(T, RD, WR)                                                    \
  {                                                                           \
    const _Float16* rd = (RD) + off0;                                         \
    const half8 hb0 = *(const half8*)(rd);                                    \
    const half8 hb1 = *(const half8*)(rd + 128);                              \
    const half8 hb2 = *(const half8*)(rd + 256);                              \
    const half8 hb3 = *(const half8*)(rd + 384);                              \
    half8 ax = {};                                                            \
    if (xv) ax = *(const half8*)(xb + (T) * 96);                              \
    f32x4 a0 = MFMA16(ax, wih_f[0], fz);                                      \
    f32x4 a1 = MFMA16(ax, wih_f[1], fz);                                      \
    f32x4 a2 = MFMA16(ax, wih_f[2], fz);                                      \
    f32x4 a3 = MFMA16(ax, wih_f[3], fz);                                      \
    a0 = MFMA16(hb0, whh_f[0][0], a0); a1 = MFMA16(hb0, whh_f[1][0], a1);     \
    a2 = MFMA16(hb0, whh_f[2][0], a2); a3 = MFMA16(hb0, whh_f[3][0], a3);     \
    a0 = MFMA16(hb1, whh_f[0][1], a0); a1 = MFMA16(hb1, whh_f[1][1], a1);     \
    a2 = MFMA16(hb1, whh_f[2][1], a2); a3 = MFMA16(hb1, whh_f[3][1], a3);     \
    a0 = MFMA16(hb2, whh_f[0][2], a0); a1 = MFMA16(hb2, whh_f[1][2], a1);     \
    a2 = MFMA16(hb2, whh_f[2][2], a2); a3 = MFMA16(hb2, whh_f[3][2], a3);     \
    a0 = MFMA16(hb3, whh_f[0][3], a0); a1 = MFMA16(hb3, whh_f[1][3], a1);     \
    a2 = MFMA16(hb3, whh_f[2][3], a2); a3 = MFMA16(hb3, whh_f[3][3], a3);     \
    const float gi = sel4(a0, lg) + bias[0];                                  \
    const float gf = sel4(a1, lg) + bias[1];                                  \
    const float gg = sel4(a2, lg) + bias[2];                                  \
    const float go = sel4(a3, lg) + bias[3];                                  \
    const float I = sigf(gi), F = sigf(gf), G = tanhf_(gg), O = sigf(go);     \
    c = F * c + I * G;                                                        \
    const float h = O * tanhf_(c);                                            \
    const _Float16 h16 = (_Float16)h;                                         \
    (WR)[woff] = h16;                                                         \
    h1p[(size_t)(T) * 131072] = h16;                                          \
    BARRIER();                                                                \
  }

#pragma unroll 1
  for (int t = 0; t < 512; t += 2) {
    L1_STEP(t, hb0p + 512, hb0p);
    L1_STEP(t + 1, hb0p, hb0p + 512);
  }
#undef L1_STEP
}

// ------- Layer 2 + Linear: producer/consumer, compact f32 gate-quad ring -------
__global__ __launch_bounds__(1024) void lstm_layer2_pc(
    const _Float16* __restrict__ h1g,   // [512][1024][128]
    const float* __restrict__ Wih,      // [512,128]
    const float* __restrict__ Whh,      // [512,128]
    const float* __restrict__ bih, const float* __restrict__ bhh,
    const float* __restrict__ Wlin,     // [7,128]
    const float* __restrict__ blin,     // [7]
    float* __restrict__ out)            // [1024, 3584]
{
  __shared__ float ring2[NSLOT][128 * 20];   // 50 KiB: [slot][col][row][4 gates]+pad
  __shared__ _Float16 h1s[4][512];           // 4 KiB: h1 glds ring (chunk-swizzled)
  __shared__ _Float16 h2b[2][512];           // 2 KiB
  __shared__ _Float16 wlls[16][136];         // Wlin staged
  const int tid = threadIdx.x, bid = blockIdx.x;
  const int wv = tid >> 6, lane = tid & 63;
  const int lg = lane >> 4, lc = lane & 15;
  const bool isCons = (wv < 8);
  const int cw = isCons ? wv : (wv - 8);
  const int col = cw * 16 + lc;
  const int off0 = lg * 32 + (lc & 3) * 8;
  const int woff = ((col >> 3) * 4 + lg) * 8 + (col & 7);
  const int roff = col * 20 + lg * 4;        // ring2 quad index (f32)

  for (int i = tid; i < 16 * 128; i += 1024)
    wlls[i >> 7][i & 127] = (_Float16)((i < 7 * 128) ? Wlin[i] : 0.f);
  for (int i = tid; i < 1024; i += 1024) ((_Float16*)h2b)[i] = (_Float16)0.f;

  // Pre-swizzled glds source (R14-proven): lane l loads global chunk
  // (l&48)|((l&15)^((l>>3)&6)) so LDS chunk r*16+c' holds row r chunk c, c'=c^2r.
  const int gchunk = (lane & 48) | ((lane & 15) ^ ((lane >> 3) & 6));
  const _Float16* h1base = h1g + (size_t)bid * 512 + gchunk * 8;
  if (wv == 8) {
    glds16(h1base, &h1s[0][0]);
    glds16(h1base + 131072, &h1s[1][0]);
    glds16(h1base + 262144, &h1s[2][0]);
    asm volatile("s_waitcnt vmcnt(2)" ::: "memory");   // slot 0 complete
  }

  if (isCons) {
    // ---------------- Consumer: recurrence (wh2 only) ----------------
    half8 wh_f[4][4];
#pragma unroll
    for (int g = 0; g < 4; ++g) {
      const int n = g * 128 + col;
#pragma unroll
      for (int kk = 0; kk < 4; ++kk) {
        const float* p = Whh + n * 128 + kk * 32 + lg * 8;
        half8 f;
#pragma unroll
        for (int j = 0; j < 8; ++j) f[j] = (_Float16)p[j];
        wh_f[g][kk] = f;
      }
      pin(wh_f[g][0]); pin(wh_f[g][1]); pin(wh_f[g][2]); pin(wh_f[g][3]);
    }
    const bool yv = (lc < 7);
    const float ybias = yv ? blin[lc] : 0.f;
    const f32x4 fz = {0.f, 0.f, 0.f, 0.f};
    __syncthreads();

    float c = 0.f;
    int slotR = 0;
#pragma unroll 1
    for (int it = 0; it < 512 + D_AHEAD; ++it) {
      if (it >= D_AHEAD) {
        const int t = it - D_AHEAD;
        const int pb = t & 1;
        const _Float16* rd = &h2b[pb ^ 1][0] + off0;
        const half8 q0 = *(const half8*)(rd);
        const half8 q1 = *(const half8*)(rd + 128);
        const half8 q2 = *(const half8*)(rd + 256);
        const half8 q3 = *(const half8*)(rd + 384);
        const f32x4 rv = *(const f32x4*)(&ring2[slotR][0] + roff);  // {i,f,g,o}
        f32x4 b0, b1, b2, b3;
        __builtin_amdgcn_s_setprio(1);
        b0 = MFMA16(q0, wh_f[0][0], fz); b1 = MFMA16(q0, wh_f[1][0], fz);
        b2 = MFMA16(q0, wh_f[2][0], fz); b3 = MFMA16(q0, wh_f[3][0], fz);
        b0 = MFMA16(q1, wh_f[0][1], b0); b1 = MFMA16(q1, wh_f[1][1], b1);
        b2 = MFMA16(q1, wh_f[2][1], b2); b3 = MFMA16(q1, wh_f[3][1], b3);
        b0 = MFMA16(q2, wh_f[0][2], b0); b1 = MFMA16(q2, wh_f[1][2], b1);
        b2 = MFMA16(q2, wh_f[2][2], b2); b3 = MFMA16(q2, wh_f[3][2], b3);
        b0 = MFMA16(q3, wh_f[0][3], b0); b1 = MFMA16(q3, wh_f[1][3], b1);
        b2 = MFMA16(q3, wh_f[2][3], b2); b3 = MFMA16(q3, wh_f[3][3], b3);
        __builtin_amdgcn_s_setprio(0);
        // y(t-1) from q = h2(t-1); wave 0 only
        if (wv == 0 && t > 0) {
          const _Float16* wlp = &wlls[lc][0] + lg * 8;
          f32x4 ya = {ybias, ybias, ybias, ybias};
          {
            const half8 w0 = *(const half8*)(wlp);
            const half8 w1 = *(const half8*)(wlp + 32);
            ya = MFMA16(q0, w0, ya);
            ya = MFMA16(q1, w1, ya);
          }
          {
            const half8 w2 = *(const half8*)(wlp + 64);
            const half8 w3 = *(const half8*)(wlp + 96);
            ya = MFMA16(q2, w2, ya);
            ya = MFMA16(q3, w3, ya);
          }
          if (lg == 0 && yv) {
#pragma unroll
            for (int j = 0; j < 4; ++j)
              out[(size_t)(bid * 4 + j) * 3584 + (size_t)(t - 1) * 7 + lc] = ya[j];
          }
        }
        const float gi = sel4(b0, lg) + rv[0];
        const float gf = sel4(b1, lg) + rv[1];
        const float gg = sel4(b2, lg) + rv[2];
        const float go = sel4(b3, lg) + rv[3];
        const float I = sigf(gi), F = sigf(gf), G = tanhf_(gg), O = sigf(go);
        c = F * c + I * G;
        h2b[pb][woff] = (_Float16)(O * tanhf_(c));
        if (++slotR == NSLOT) slotR = 0;
      }
      BARRIER();
    }
    // final y(511): h2(511) in h2b[1]
    if (wv == 0) {
      const _Float16* rd = &h2b[1][0] + off0;
      const half8 q0 = *(const half8*)(rd);
      const half8 q1 = *(const half8*)(rd + 128);
      const half8 q2 = *(const half8*)(rd + 256);
      const half8 q3 = *(const half8*)(rd + 384);
      const _Float16* wlp = &wlls[lc][0] + lg * 8;
      const half8 w0 = *(const half8*)(wlp);
      const half8 w1 = *(const half8*)(wlp + 32);
      const half8 w2 = *(const half8*)(wlp + 64);
      const half8 w3 = *(const half8*)(wlp + 96);
      f32x4 ya = {ybias, ybias, ybias, ybias};
      ya = MFMA16(q0, w0, ya);
      ya = MFMA16(q1, w1, ya);
      ya = MFMA16(q2, w2, ya);
      ya = MFMA16(q3, w3, ya);
      if (lg == 0 && yv) {
#pragma unroll
        for (int j = 0; j < 4; ++j)
          out[(size_t)(bid * 4 + j) * 3584 + (size_t)511 * 7 + lc] = ya[j];
      }
    }
  } else {
    // ---------- Producer: a(t) = bias2 + wi2*h1(t), D ahead, swizzled h1s ----------
    half8 wi_f[4][4];
    float bias_s[4];
#pragma unroll
    for (int g = 0; g < 4; ++g) {
      const int n = g * 128 + col;
      bias_s[g] = bih[n] + bhh[n];
#pragma unroll
      for (int kk = 0; kk < 4; ++kk) {
        const float* p = Wih + n * 128 + kk * 32 + lg * 8;
        half8 f;
#pragma unroll
        for (int j = 0; j < 8; ++j) f[j] = (_Float16)p[j];
        wi_f[g][kk] = f;
      }
      pin(wi_f[g][0]); pin(wi_f[g][1]); pin(wi_f[g][2]); pin(wi_f[g][3]);
    }
    const f32x4 bV0 = {bias_s[0], bias_s[0], bias_s[0], bias_s[0]};
    const f32x4 bV1 = {bias_s[1], bias_s[1], bias_s[1], bias_s[1]};
    const f32x4 bV2 = {bias_s[2], bias_s[2], bias_s[2], bias_s[2]};
    const f32x4 bV3 = {bias_s[3], bias_s[3], bias_s[3], bias_s[3]};
    // swizzled h1s read offsets (halfs): chunk = row*16 + ((kk*4+lg) ^ 2*row)
    const int hrow = lc & 3;
    int hofs[4];
#pragma unroll
    for (int kk = 0; kk < 4; ++kk)
      hofs[kk] = hrow * 128 + (((kk * 4 + lg) ^ (hrow << 1)) << 3);
    __syncthreads();

    int slotW = 0;
#pragma unroll 1
    for (int it = 0; it < 512 + D_AHEAD; ++it) {
      if (it < 512) {
        // issue h1(it+3) into LDS ring, 3 barrier-intervals ahead
        if (wv == 8 && it + 3 < 512)
          glds16(h1base + (size_t)(it + 3) * 131072, &h1s[(it + 3) & 3][0]);
        const _Float16* hp = &h1s[it & 3][0];
        const half8 p0 = *(const half8*)(hp + hofs[0]);
        const half8 p1 = *(const half8*)(hp + hofs[1]);
        const half8 p2 = *(const half8*)(hp + hofs[2]);
        const half8 p3 = *(const half8*)(hp + hofs[3]);
        f32x4 a0 = MFMA16(p0, wi_f[0][0], bV0);
        f32x4 a1 = MFMA16(p0, wi_f[1][0], bV1);
        f32x4 a2 = MFMA16(p0, wi_f[2][0], bV2);
        f32x4 a3 = MFMA16(p0, wi_f[3][0], bV3);
        a0 = MFMA16(p1, wi_f[0][1], a0); a1 = MFMA16(p1, wi_f[1][1], a1);
        a2 = MFMA16(p1, wi_f[2][1], a2); a3 = MFMA16(p1, wi_f[3][1], a3);
        a0 = MFMA16(p2, wi_f[0][2], a0); a1 = MFMA16(p2, wi_f[1][2], a1);
        a2 = MFMA16(p2, wi_f[2][2], a2); a3 = MFMA16(p2, wi_f[3][2], a3);
        a0 = MFMA16(p3, wi_f[0][3], a0); a1 = MFMA16(p3, wi_f[1][3], a1);
        a2 = MFMA16(p3, wi_f[2][3], a2); a3 = MFMA16(p3, wi_f[3][3], a3);
        // sel4-transpose: lane (lg,lc) writes {i,f,g,o} for (row lg, col) --
        // all 64 lanes active, ONE ds_write_b128.
        {
          f32x4 v;
          v[0] = sel4(a0, lg);
          v[1] = sel4(a1, lg);
          v[2] = sel4(a2, lg);
          v[3] = sel4(a3, lg);
          *(f32x4*)(&ring2[slotW][0] + roff) = v;
        }
        // keep <=2 glds in flight; guarantees slot (it+1) complete
        if (wv == 8) asm volatile("s_waitcnt vmcnt(2)" ::: "memory");
        if (++slotW == NSLOT) slotW = 0;
      }
      BARRIER();
    }
  }
}

extern "C" void kernel_launch(void* const* d_in, const int* in_sizes, int n_in,
                              void* d_out, int out_size, void* d_ws, size_t ws_size,
                              hipStream_t stream) {
  (void)in_sizes; (void)n_in; (void)out_size; (void)ws_size;
  const float* x     = (const float*)d_in[0];
  const float* W_ih1 = (const float*)d_in[1];
  const float* W_hh1 = (const float*)d_in[2];
  const float* b_ih1 = (const float*)d_in[3];
  const float* b_hh1 = (const float*)d_in[4];
  const float* W_ih2 = (const float*)d_in[5];
  const float* W_hh2 = (const float*)d_in[6];
  const float* b_ih2 = (const float*)d_in[7];
  const float* b_hh2 = (const float*)d_in[8];
  const float* W_lin = (const float*)d_in[9];
  const float* b_lin = (const float*)d_in[10];
  float* out = (float*)d_out;
  _Float16* h1g = (_Float16*)d_ws;   // [512][1024][128] fp16 = 134,217,728 bytes

  lstm_layer1_kernel<<<256, 512, 0, stream>>>(x, W_ih1, W_hh1, b_ih1, b_hh1, h1g);
  lstm_layer2_pc<<<256, 1024, 0, stream>>>(h1g, W_ih2, W_hh2, b_ih2, b_hh2,
                                           W_lin, b_lin, out);
}